// Round 5
// baseline (8378.856 us; speedup 1.0000x reference)
//
#include <hip/hip_runtime.h>
#include <hip/hip_bf16.h>
#include <math.h>

#define B_ 256
#define D_ 768
#define N_ 256
#define L_ 2
#define H_ 8
#define T_ 20
#define HD_ 96
#define D4_ 3072

typedef float f32x4v __attribute__((ext_vector_type(4)));
typedef __bf16 bf16x8v __attribute__((ext_vector_type(8)));

union V16 { uint4 u; bf16x8v v; };

__device__ __forceinline__ ushort f2b(float f) {
    union { float f; unsigned u; } x{f};
    unsigned r = x.u + 0x7fffu + ((x.u >> 16) & 1u);
    return (ushort)(r >> 16);
}
__device__ __forceinline__ float b2f(ushort s) {
    union { unsigned u; float f; } x{(unsigned)s << 16};
    return x.f;
}
__device__ __forceinline__ float gelu_f(float v) {
    return 0.5f * v * (1.0f + erff(v * 0.7071067811865476f));
}
__device__ __forceinline__ float dot8(const float* __restrict__ xp, uint4 u) {
    return xp[0] * b2f((ushort)(u.x & 0xffffu)) + xp[1] * b2f((ushort)(u.x >> 16))
         + xp[2] * b2f((ushort)(u.y & 0xffffu)) + xp[3] * b2f((ushort)(u.y >> 16))
         + xp[4] * b2f((ushort)(u.z & 0xffffu)) + xp[5] * b2f((ushort)(u.z >> 16))
         + xp[6] * b2f((ushort)(u.w & 0xffffu)) + xp[7] * b2f((ushort)(u.w >> 16));
}
__device__ __forceinline__ float blockSum(float v, float* red, int tid) {
    for (int off = 32; off; off >>= 1) v += __shfl_down(v, off, 64);
    int w = tid >> 6, lane = tid & 63;
    if (lane == 0) red[w] = v;
    __syncthreads();
    float r = red[0] + red[1] + red[2] + red[3];
    __syncthreads();
    return r;
}
// async global->LDS, 16B per lane; lds base must be wave-uniform (lane*16 added by HW)
__device__ __forceinline__ void gl_lds16(const ushort* g, ushort* l) {
    __builtin_amdgcn_global_load_lds((const __attribute__((address_space(1))) unsigned int*)g,
                                     (__attribute__((address_space(3))) unsigned int*)l,
                                     16, 0, 0);
}

// ---------------- context + cp init + prestep(t=0); writes BOTH x buffers ----------------
__global__ __launch_bounds__(256) void context_kernel(const float* __restrict__ past,
                                                      const float* __restrict__ w_qinit,
                                                      const float* __restrict__ b_qinit,
                                                      const int* __restrict__ intent,
                                                      const float* __restrict__ w_pp,
                                                      const float* __restrict__ b_pp,
                                                      const float* __restrict__ g_pp,
                                                      const float* __restrict__ be_pp,
                                                      const float* __restrict__ te0,
                                                      float* __restrict__ xA,
                                                      float* __restrict__ xB,
                                                      float* __restrict__ cp) {
    int b = blockIdx.x, tid = threadIdx.x;
    __shared__ float ps[96];
    __shared__ int oidx;
    __shared__ float red[4];
    if (tid < 96) ps[tid] = past[b * 96 + tid];
    if (tid == 0) {
        int iv = intent[b] - 1;
        oidx = iv < 0 ? 0 : (iv > 2 ? 2 : iv);
    }
    __syncthreads();
    float ctx[3];
    #pragma unroll
    for (int r = 0; r < 3; ++r) {
        int d = tid + r * 256;
        float acc = w_qinit[oidx * D_ + d] + b_qinit[d];
        #pragma unroll 8
        for (int p = 0; p < 96; ++p) acc += ps[p] * w_qinit[(3 + p) * D_ + d];
        ctx[r] = acc;
    }
    float c0 = ps[90], c1 = ps[91];   // past[:, -1, 0:2]
    if (tid == 0) { cp[b * 2] = c0; cp[b * 2 + 1] = c1; }
    // prestep for t=0
    float t[3];
    float s = 0, ss = 0;
    #pragma unroll
    for (int r = 0; r < 3; ++r) {
        int d = tid + r * 256;
        t[r] = c0 * w_pp[d] + c1 * w_pp[D_ + d] + b_pp[d];
        s += t[r]; ss += t[r] * t[r];
    }
    s = blockSum(s, red, tid);
    ss = blockSum(ss, red, tid);
    float mean = s * (1.0f / D_);
    float var = ss * (1.0f / D_) - mean * mean;
    float rinv = rsqrtf(var + 1e-5f);
    #pragma unroll
    for (int r = 0; r < 3; ++r) {
        int d = tid + r * 256;
        float pq = fmaxf((t[r] - mean) * rinv * g_pp[d] + be_pp[d], 0.0f);
        float nv = ctx[r] + pq + te0[d];
        xA[b * D_ + d] = nv;
        xB[b * D_ + d] = nv;
    }
}

// ---------------- tokens bf16 k-major ----------------
__global__ __launch_bounds__(256) void token_prep(const float* __restrict__ feats,
                                                  const float* __restrict__ pos_enc,
                                                  ushort* __restrict__ tokens) {
    int b = blockIdx.z;
    int d0 = blockIdx.x * 64, n0 = blockIdx.y * 64;
    __shared__ float tile[64][65];
    int tid = threadIdx.x;
    int nl = tid & 63, dl0 = tid >> 6;
    const float* fb = feats + ((size_t)b * D_ + d0) * N_ + n0;
    #pragma unroll
    for (int i = 0; i < 16; ++i) {
        int dl = dl0 + i * 4;
        tile[dl][nl] = fb[(size_t)dl * N_ + nl];
    }
    __syncthreads();
    int dq = (tid & 15) * 4;
    int ng = tid >> 4;
    #pragma unroll
    for (int i = 0; i < 4; ++i) {
        int nl2 = ng + i * 16;
        int n = n0 + nl2;
        float4 p = *(const float4*)(pos_enc + (size_t)n * D_ + d0 + dq);
        ushort4 o;
        o.x = f2b(tile[dq + 0][nl2] + p.x);
        o.y = f2b(tile[dq + 1][nl2] + p.y);
        o.z = f2b(tile[dq + 2][nl2] + p.z);
        o.w = f2b(tile[dq + 3][nl2] + p.w);
        *(ushort4*)&tokens[((size_t)b * N_ + n) * D_ + d0 + dq] = o;
    }
}

// ---------------- weight transpose (+ optional row scale) fp32[K][N] -> bf16[N][K] ----------------
__global__ __launch_bounds__(256) void transpose_w(const float* __restrict__ W,
                                                   ushort* __restrict__ out,
                                                   const float* __restrict__ scale,
                                                   int K, int N) {
    __shared__ float t[32][33];
    int k0 = blockIdx.y * 32, n0 = blockIdx.x * 32;
    int tx = threadIdx.x & 31, ty = threadIdx.x >> 5;
    #pragma unroll
    for (int i = 0; i < 4; ++i)
        t[ty + i * 8][tx] = W[(size_t)(k0 + ty + i * 8) * N + n0 + tx];
    __syncthreads();
    #pragma unroll
    for (int i = 0; i < 4; ++i) {
        int n = n0 + ty + i * 8, k = k0 + tx;
        float v = t[tx][ty + i * 8];
        if (scale) v *= scale[k];
        out[(size_t)n * K + k] = f2b(v);
    }
}

// ---------------- bias_eff = bias + b_ln @ W (parallel k-split) ----------------
__global__ __launch_bounds__(256) void bias_eff_kernel(const float* __restrict__ W,
                                                       const float* __restrict__ bias,
                                                       const float* __restrict__ lb,
                                                       float* __restrict__ be, int Nc) {
    __shared__ float lbs[768];
    __shared__ float part[4][64];
    int tid = threadIdx.x;
    for (int i = tid; i < 768; i += 256) lbs[i] = lb[i];
    __syncthreads();
    int n0 = blockIdx.x * 64;
    int nl = tid & 63, kp = tid >> 6;
    int n = n0 + nl;
    float a = 0.0f;
    #pragma unroll 4
    for (int k = kp * 192; k < kp * 192 + 192; ++k)
        a += lbs[k] * W[(size_t)k * Nc + n];
    part[kp][nl] = a;
    __syncthreads();
    if (tid < 64)
        be[n0 + tid] = bias[n0 + tid] + part[0][tid] + part[1][tid] + part[2][tid] + part[3][tid];
}

__global__ void kvbias_prep(const float* __restrict__ bk, const float* __restrict__ bv,
                            float* __restrict__ bc) {
    int i = blockIdx.x * 256 + threadIdx.x;
    int mi = i / D_, c = i % D_;
    int l = mi >> 1;
    bc[i] = (mi & 1 ? bv : bk)[l * D_ + c];
}

// ---------------- K/V projection MFMA GEMM (both K and V stored hd-major [.. hd][n]) ----------------
// R1 form: global_load_lds double-buffered staging, linear LDS [row][32], no swizzle
__global__ __launch_bounds__(256) void kv_gemm_mfma(const ushort* __restrict__ tokens,
                                                    const ushort* __restrict__ Wkvt,
                                                    const float* __restrict__ bias_kv,
                                                    ushort* __restrict__ Kt,
                                                    ushort* __restrict__ Vt) {
    int e0 = blockIdx.x * 128;
    int mi = e0 / D_;
    int ein = e0 % D_;
    int l = mi >> 1, isV = mi & 1;
    int m0 = blockIdx.y * 128;
    int b = m0 >> 8, ntok0 = m0 & 255;
    __shared__ __align__(16) ushort smem[17408];
    int tid = threadIdx.x;
    int w = tid >> 6, lane = tid & 63, quad = lane >> 4, l16 = lane & 15;
    int wr = w >> 1, wc = w & 1;
    f32x4v acc[4][4];
    #pragma unroll
    for (int i = 0; i < 4; ++i)
        #pragma unroll
        for (int j = 0; j < 4; ++j) acc[i][j] = (f32x4v)(0.0f);

    auto stage = [&](int buf, int k0) {
        ushort* Ab = smem + buf * 8192;
        ushort* Bb = Ab + 4096;
        #pragma unroll
        for (int vv = 0; vv < 2; ++vv) {
            int v = tid + vv * 256;
            int row = v >> 2, kv = v & 3;
            gl_lds16(&tokens[(size_t)(m0 + row) * D_ + k0 + kv * 8], Ab + w * 512 + vv * 2048);
            gl_lds16(&Wkvt[(size_t)(e0 + row) * D_ + k0 + kv * 8],   Bb + w * 512 + vv * 2048);
        }
    };

    stage(0, 0);
    asm volatile("s_waitcnt vmcnt(0)" ::: "memory");
    __syncthreads();
    int cur = 0;
    for (int k0 = 0; k0 < D_; k0 += 32) {
        if (k0 + 32 < D_) stage(cur ^ 1, k0 + 32);
        const ushort* Ab = smem + cur * 8192;
        const ushort* Bb = Ab + 4096;
        V16 a[4], bb[4];
        #pragma unroll
        for (int i = 0; i < 4; ++i)
            a[i].u = *(const uint4*)&Ab[(wr * 64 + i * 16 + l16) * 32 + quad * 8];
        #pragma unroll
        for (int j = 0; j < 4; ++j)
            bb[j].u = *(const uint4*)&Bb[(wc * 64 + j * 16 + l16) * 32 + quad * 8];
        #pragma unroll
        for (int i = 0; i < 4; ++i)
            #pragma unroll
            for (int j = 0; j < 4; ++j)
                acc[i][j] = __builtin_amdgcn_mfma_f32_16x16x32_bf16(a[i].v, bb[j].v, acc[i][j], 0, 0, 0);
        asm volatile("s_waitcnt vmcnt(0)" ::: "memory");
        __syncthreads();
        cur ^= 1;
    }

    float bcol[4];
    #pragma unroll
    for (int j = 0; j < 4; ++j)
        bcol[j] = bias_kv[e0 + wc * 64 + j * 16 + l16];

    ushort* Ct = smem;
    ushort* outbuf = isV ? Vt : Kt;
    #pragma unroll
    for (int i = 0; i < 4; ++i)
        #pragma unroll
        for (int j = 0; j < 4; ++j) {
            int e_l = wc * 64 + j * 16 + l16;
            int m_b = wr * 64 + i * 16 + quad * 4;
            ushort4 p;
            p.x = f2b(acc[i][j][0] + bcol[j]);
            p.y = f2b(acc[i][j][1] + bcol[j]);
            p.z = f2b(acc[i][j][2] + bcol[j]);
            p.w = f2b(acc[i][j][3] + bcol[j]);
            *(ushort4*)&Ct[e_l * 136 + m_b] = p;
        }
    __syncthreads();
    int e_l = tid >> 1, half = tid & 1;
    int c = ein + e_l;
    int h = c / HD_, hd = c % HD_;
    size_t dst = ((((size_t)l * B_ + b) * H_ + h) * HD_ + hd) * N_ + ntok0 + half * 64;
    #pragma unroll
    for (int p8 = 0; p8 < 8; ++p8)
        *(uint4*)&outbuf[dst + p8 * 8] = *(const uint4*)&Ct[e_l * 136 + half * 64 + p8 * 8];
}

// ---------------- small MFMA GEMM, async 2-phase pipeline, swizzled LDS ----------------
// AVAR: 0 = bf16 A (global_load_lds), 1 = fp32 A normalized by inline row stats (reg path)
// OMODE: 0 = bf16 store, 1 = gelu->bf16 store, 2 = fp32 atomicAdd (bias on z==0; dual-buffer if Cv2)
// xcopy: when STATS, blockIdx.x==0 blocks mirror the A rows into xcopy (ping-pong refresh)
template<int AVAR, int OMODE, int STATS, int KSPLIT>
__global__ __launch_bounds__(256) void gemm_s(const void* __restrict__ Av,
                                              const ushort* __restrict__ Bt,
                                              const float* __restrict__ bias,
                                              void* __restrict__ Cv,
                                              float* __restrict__ Cv2,
                                              float* __restrict__ xcopy,
                                              int K, int Nc) {
    __shared__ __align__(16) ushort As[2][2048];
    __shared__ __align__(16) ushort Bs[2][2048];
    __shared__ float smst[64][2];
    int tid = threadIdx.x;
    int m0 = blockIdx.y * 64, e0 = blockIdx.x * 64;
    int kslice = K / KSPLIT;
    int kbeg = blockIdx.z * kslice, kend = kbeg + kslice;
    int w = tid >> 6, lane = tid & 63, quad = lane >> 4, l16 = lane & 15;
    int swz = (l16 >> 1) & 3;
    int rchunk = ((quad ^ swz) & 3) * 8;

    if (STATS) {
        // inline LN stats for rows m0..m0+63 (4 threads/row, K==768)
        int row = tid >> 2, part = tid & 3;
        const float* xr = (const float*)Av + (size_t)(m0 + row) * K + part * 192;
        float* xc = xcopy ? xcopy + (size_t)(m0 + row) * K + part * 192 : nullptr;
        bool doCopy = xcopy && blockIdx.x == 0;
        float s = 0, ss = 0;
        #pragma unroll 4
        for (int i = 0; i < 192; i += 4) {
            float4 f = *(const float4*)(xr + i);
            if (doCopy) *(float4*)(xc + i) = f;
            s += f.x + f.y + f.z + f.w;
            ss += f.x * f.x + f.y * f.y + f.z * f.z + f.w * f.w;
        }
        s += __shfl_xor(s, 1, 64);  s += __shfl_xor(s, 2, 64);
        ss += __shfl_xor(ss, 1, 64); ss += __shfl_xor(ss, 2, 64);
        if (part == 0) {
            float mean = s * (1.0f / 768.0f);
            float var = ss * (1.0f / 768.0f) - mean * mean;
            smst[row][0] = mean;
            smst[row][1] = rsqrtf(var + 1e-5f);
        }
        __syncthreads();
    }

    bool doA = w < 2;
    int t2 = tid & 127;
    f32x4v acc[4];
    #pragma unroll
    for (int i = 0; i < 4; ++i) acc[i] = (f32x4v)(0.0f);

    auto fetchA1 = [&](int kk, int vv) -> uint4 {
        int v = t2 + vv * 128;
        int row = v >> 2, kq = v & 3;
        const float* Af = (const float*)Av + (size_t)(m0 + row) * K + kk + kq * 8;
        float4 f0 = *(const float4*)Af;
        float4 f1 = *(const float4*)(Af + 4);
        float mn = smst[row][0], rs = smst[row][1];
        f0.x = (f0.x - mn) * rs; f0.y = (f0.y - mn) * rs;
        f0.z = (f0.z - mn) * rs; f0.w = (f0.w - mn) * rs;
        f1.x = (f1.x - mn) * rs; f1.y = (f1.y - mn) * rs;
        f1.z = (f1.z - mn) * rs; f1.w = (f1.w - mn) * rs;
        uint4 u;
        u.x = (unsigned)f2b(f0.x) | ((unsigned)f2b(f0.y) << 16);
        u.y = (unsigned)f2b(f0.z) | ((unsigned)f2b(f0.w) << 16);
        u.z = (unsigned)f2b(f1.x) | ((unsigned)f2b(f1.y) << 16);
        u.w = (unsigned)f2b(f1.z) | ((unsigned)f2b(f1.w) << 16);
        return u;
    };
    auto stashA = [&](int buf, int vv, uint4 u) {
        int v = t2 + vv * 128;
        int row = v >> 2, kq = v & 3;
        *(uint4*)&As[buf][row * 32 + ((kq ^ ((row >> 1) & 3)) & 3) * 8] = u;
    };
    auto stageA0 = [&](int buf, int kk) {
        #pragma unroll
        for (int vv = 0; vv < 2; ++vv) {
            int v = t2 + vv * 128;
            int row = v >> 2;
            int kq = (v & 3) ^ ((row >> 1) & 3);
            gl_lds16((const ushort*)Av + (size_t)(m0 + row) * K + kk + kq * 8,
                     &As[buf][w * 512 + vv * 1024]);
        }
    };
    auto stageB = [&](int buf, int kk) {
        int wb = w - 2;
        #pragma unroll
        for (int vv = 0; vv < 2; ++vv) {
            int v = t2 + vv * 128;
            int row = v >> 2;
            int kq = (v & 3) ^ ((row >> 1) & 3);
            gl_lds16(&Bt[(size_t)(e0 + row) * K + kk + kq * 8],
                     &Bs[buf][wb * 512 + vv * 1024]);
        }
    };
    auto compute = [&](int buf) {
        V16 bb;
        bb.u = *(const uint4*)&Bs[buf][(w * 16 + l16) * 32 + rchunk];
        #pragma unroll
        for (int i = 0; i < 4; ++i) {
            V16 a;
            a.u = *(const uint4*)&As[buf][(i * 16 + l16) * 32 + rchunk];
            acc[i] = __builtin_amdgcn_mfma_f32_16x16x32_bf16(a.v, bb.v, acc[i], 0, 0, 0);
        }
    };

    // prologue
    if (doA) {
        if (AVAR == 0) {
            stageA0(0, kbeg);
        } else {
            uint4 p0 = fetchA1(kbeg, 0), p1 = fetchA1(kbeg, 1);
            stashA(0, 0, p0); stashA(0, 1, p1);
        }
    } else {
        stageB(0, kbeg);
    }
    asm volatile("s_waitcnt vmcnt(0)" ::: "memory");
    __syncthreads();
    int cur = 0;
    for (int kk = kbeg + 32; kk < kend; kk += 32) {
        uint4 p0, p1;
        if (doA) {
            if (AVAR == 0) stageA0(cur ^ 1, kk);
            else { p0 = fetchA1(kk, 0); p1 = fetchA1(kk, 1); }
        } else {
            stageB(cur ^ 1, kk);
        }
        compute(cur);
        if (AVAR == 1 && doA) { stashA(cur ^ 1, 0, p0); stashA(cur ^ 1, 1, p1); }
        asm volatile("s_waitcnt vmcnt(0)" ::: "memory");
        __syncthreads();
        cur ^= 1;
    }
    compute(cur);

    int n = e0 + w * 16 + l16;
    float bn = 0.0f;
    if (OMODE != 2 || blockIdx.z == 0) bn = bias[n];
    #pragma unroll
    for (int i = 0; i < 4; ++i) {
        #pragma unroll
        for (int r = 0; r < 4; ++r) {
            int m = m0 + i * 16 + quad * 4 + r;
            float v = acc[i][r] + bn;
            if (OMODE == 1) v = gelu_f(v);
            if (OMODE == 2) {
                atomicAdd((float*)Cv + (size_t)m * Nc + n, v);
                if (Cv2) atomicAdd(Cv2 + (size_t)m * Nc + n, v);
            } else {
                ((ushort*)Cv)[(size_t)m * Nc + n] = f2b(v);
            }
        }
    }
}

// ---------------- fused LN1 + Q-projection + attention + output projection ----------------
// one block per (b,h); K and V both hd-major: [.., hd, n]
// reads xin (stable), atomicAdds o@Wo (+bo on h==0) into xout
__global__ __launch_bounds__(256) void attn_fused(const float* __restrict__ xin,
                                                  const ushort* __restrict__ Wqt,
                                                  const float* __restrict__ bqe,
                                                  const ushort* __restrict__ Kt,
                                                  const ushort* __restrict__ Vt,
                                                  const ushort* __restrict__ Wot,
                                                  const float* __restrict__ bo,
                                                  float* __restrict__ xout) {
    int b = blockIdx.y, h = blockIdx.x, tid = threadIdx.x;
    int w = tid >> 6, lane = tid & 63;
    __shared__ float xs[768];
    __shared__ float red[4];
    __shared__ float qs[96];
    __shared__ float spart[4][256];
    __shared__ float sc[256];
    __shared__ float opo[96];

    if (tid < 192) *(float4*)&xs[tid * 4] = *(const float4*)&xin[(size_t)b * D_ + tid * 4];
    __syncthreads();

    // LN stats over the row
    float s = 0, ss = 0;
    #pragma unroll
    for (int r = 0; r < 3; ++r) { float v = xs[tid + r * 256]; s += v; ss += v * v; }
    s = blockSum(s, red, tid);
    ss = blockSum(ss, red, tid);
    float mean = s * (1.0f / D_);
    float var = ss * (1.0f / D_) - mean * mean;
    float rinv = rsqrtf(var + 1e-5f);
    #pragma unroll
    for (int r = 0; r < 3; ++r) { int d = tid + r * 256; xs[d] = (xs[d] - mean) * rinv; }
    __syncthreads();

    // Q projection for this head's 96 columns: 192 threads, (col, k-half)
    if (tid < 192) {
        int j = tid >> 1, kh = tid & 1;
        const ushort* wr = Wqt + (size_t)(h * HD_ + j) * D_ + kh * 384;
        const float* xp = xs + kh * 384;
        float acc = 0.0f;
        #pragma unroll 4
        for (int k = 0; k < 384; k += 8)
            acc += dot8(xp + k, *(const uint4*)&wr[k]);
        acc += __shfl_xor(acc, 1, 64);
        if (kh == 0) qs[j] = (acc + bqe[h * HD_ + j]) * 0.10206207261596575f;
    }
    __syncthreads();

    // scores: wave w -> hd rows [w*24, w*24+24); lane: r2 = hd parity, tg covers 8 tokens (uint4)
    {
        int r2 = lane >> 5, tg = lane & 31;
        const ushort* Kp = Kt + (size_t)(b * H_ + h) * HD_ * N_;
        float s8[8];
        #pragma unroll
        for (int j = 0; j < 8; ++j) s8[j] = 0.0f;
        #pragma unroll 4
        for (int i = 0; i < 12; ++i) {
            int hd = w * 24 + i * 2 + r2;
            uint4 kk = *(const uint4*)&Kp[hd * N_ + tg * 8];
            float qv = qs[hd];
            s8[0] += qv * b2f((ushort)(kk.x & 0xffffu));
            s8[1] += qv * b2f((ushort)(kk.x >> 16));
            s8[2] += qv * b2f((ushort)(kk.y & 0xffffu));
            s8[3] += qv * b2f((ushort)(kk.y >> 16));
            s8[4] += qv * b2f((ushort)(kk.z & 0xffffu));
            s8[5] += qv * b2f((ushort)(kk.z >> 16));
            s8[6] += qv * b2f((ushort)(kk.w & 0xffffu));
            s8[7] += qv * b2f((ushort)(kk.w >> 16));
        }
        #pragma unroll
        for (int j = 0; j < 8; ++j) s8[j] += __shfl_xor(s8[j], 32, 64);
        if (r2 == 0) {
            float4 lo, hi;
            lo.x = s8[0]; lo.y = s8[1]; lo.z = s8[2]; lo.w = s8[3];
            hi.x = s8[4]; hi.y = s8[5]; hi.z = s8[6]; hi.w = s8[7];
            *(float4*)&spart[w][tg * 8] = lo;
            *(float4*)&spart[w][tg * 8 + 4] = hi;
        }
    }
    __syncthreads();

    // softmax over 256 tokens (token n = tid)
    float sv = spart[0][tid] + spart[1][tid] + spart[2][tid] + spart[3][tid];
    float m = sv;
    for (int off = 32; off; off >>= 1) m = fmaxf(m, __shfl_xor(m, off, 64));
    if (lane == 0) red[w] = m;
    __syncthreads();
    m = fmaxf(fmaxf(red[0], red[1]), fmaxf(red[2], red[3]));
    __syncthreads();
    float e = expf(sv - m);
    float tot = blockSum(e, red, tid);
    sc[tid] = e / tot;
    __syncthreads();

    // PV: 192 threads, (hd, n-half); V row contiguous over n -> uint4 loads
    if (tid < 192) {
        int hd = tid >> 1, nh = tid & 1;
        const ushort* Vr = Vt + (size_t)(b * H_ + h) * HD_ * N_ + hd * N_ + nh * 128;
        const float* scp = sc + nh * 128;
        float o = 0.0f;
        #pragma unroll 4
        for (int i = 0; i < 16; ++i)
            o += dot8(scp + i * 8, *(const uint4*)&Vr[i * 8]);
        o += __shfl_xor(o, 1, 64);
        if (nh == 0) opo[hd] = o;
    }
    __syncthreads();

    // fused output projection: xout[b,:] += opo @ Wot[:, h*96:(h+1)*96]^T  (+ bo on h==0)
    #pragma unroll
    for (int r = 0; r < 3; ++r) {
        int n = tid + r * 256;
        const ushort* wr = Wot + (size_t)n * D_ + h * HD_;
        float a = 0.0f;
        #pragma unroll
        for (int j8 = 0; j8 < 12; ++j8)
            a += dot8(opo + j8 * 8, *(const uint4*)&wr[j8 * 8]);
        if (h == 0) a += bo[n];
        atomicAdd(&xout[(size_t)b * D_ + n], a);
    }
}

// ---------------- tail: dec1 matvec + gelu + dec2 + cp update + out + prestep(t+1) ----------------
// reads xB (== xA); writes prestep result to BOTH buffers
__global__ __launch_bounds__(256) void tail_kernel(const float* __restrict__ xB,
                                                   float* __restrict__ xA,
                                                   float* __restrict__ xB2,
                                                   const ushort* __restrict__ dec1t,
                                                   const float* __restrict__ b_dec1,
                                                   const float* __restrict__ w_dec2,
                                                   const float* __restrict__ b_dec2,
                                                   float* __restrict__ cp,
                                                   float* __restrict__ out,
                                                   const float* __restrict__ time_emb,
                                                   const float* __restrict__ w_pp,
                                                   const float* __restrict__ b_pp,
                                                   const float* __restrict__ g_pp,
                                                   const float* __restrict__ be_pp,
                                                   int t) {
    int b = blockIdx.x, tid = threadIdx.x;
    __shared__ float xs[768];
    __shared__ float red[4];
    #pragma unroll
    for (int r = 0; r < 3; ++r) xs[tid + r * 256] = xB[b * D_ + tid + r * 256];
    __syncthreads();
    float d0 = 0, d1 = 0, d2 = 0;
    const ushort* w0 = dec1t + (size_t)tid * D_;
    const ushort* w1 = w0 + (size_t)256 * D_;
    const ushort* w2 = w0 + (size_t)512 * D_;
    #pragma unroll 2
    for (int k = 0; k < 768; k += 8) {
        d0 += dot8(xs + k, *(const uint4*)&w0[k]);
        d1 += dot8(xs + k, *(const uint4*)&w1[k]);
        d2 += dot8(xs + k, *(const uint4*)&w2[k]);
    }
    float v0 = gelu_f(d0 + b_dec1[tid]);
    float v1 = gelu_f(d1 + b_dec1[tid + 256]);
    float v2 = gelu_f(d2 + b_dec1[tid + 512]);
    float p0 = v0 * w_dec2[tid * 2]     + v1 * w_dec2[(tid + 256) * 2]     + v2 * w_dec2[(tid + 512) * 2];
    float p1 = v0 * w_dec2[tid * 2 + 1] + v1 * w_dec2[(tid + 256) * 2 + 1] + v2 * w_dec2[(tid + 512) * 2 + 1];
    p0 = blockSum(p0, red, tid);
    p1 = blockSum(p1, red, tid);
    float c0 = cp[b * 2] + p0 + b_dec2[0];
    float c1 = cp[b * 2 + 1] + p1 + b_dec2[1];
    if (tid == 0) {
        cp[b * 2] = c0;
        cp[b * 2 + 1] = c1;
        out[(b * T_ + t) * 2] = c0;
        out[(b * T_ + t) * 2 + 1] = c1;
    }
    if (t < T_ - 1) {
        const float* te = time_emb + (size_t)(t + 1) * D_;
        float tv[3];
        float s = 0, ss = 0;
        #pragma unroll
        for (int r = 0; r < 3; ++r) {
            int d = tid + r * 256;
            tv[r] = c0 * w_pp[d] + c1 * w_pp[D_ + d] + b_pp[d];
            s += tv[r]; ss += tv[r] * tv[r];
        }
        s = blockSum(s, red, tid);
        ss = blockSum(ss, red, tid);
        float mean = s * (1.0f / D_);
        float var = ss * (1.0f / D_) - mean * mean;
        float rinv = rsqrtf(var + 1e-5f);
        #pragma unroll
        for (int r = 0; r < 3; ++r) {
            int d = tid + r * 256;
            float pq = fmaxf((tv[r] - mean) * rinv * g_pp[d] + be_pp[d], 0.0f);
            float nv = xs[tid + r * 256] + pq + te[d];
            xA[b * D_ + d] = nv;
            xB2[b * D_ + d] = nv;
        }
    }
}

extern "C" void kernel_launch(void* const* d_in, const int* in_sizes, int n_in,
                              void* d_out, int out_size, void* d_ws, size_t ws_size,
                              hipStream_t stream) {
    const float* feats   = (const float*)d_in[0];
    const float* past    = (const float*)d_in[1];
    const float* w_qinit = (const float*)d_in[2];
    const float* b_qinit = (const float*)d_in[3];
    const float* pos_enc = (const float*)d_in[4];
    const float* w_pp    = (const float*)d_in[5];
    const float* b_pp    = (const float*)d_in[6];
    const float* g_pp    = (const float*)d_in[7];
    const float* be_pp   = (const float*)d_in[8];
    const float* time_emb= (const float*)d_in[9];
    const float* Wq      = (const float*)d_in[10];
    const float* bq      = (const float*)d_in[11];
    const float* Wk      = (const float*)d_in[12];
    const float* bk      = (const float*)d_in[13];
    const float* Wv      = (const float*)d_in[14];
    const float* bv      = (const float*)d_in[15];
    const float* Wo      = (const float*)d_in[16];
    const float* bo      = (const float*)d_in[17];
    const float* ln1_g   = (const float*)d_in[18];
    const float* ln1_b   = (const float*)d_in[19];
    const float* W1      = (const float*)d_in[20];
    const float* b1      = (const float*)d_in[21];
    const float* W2      = (const float*)d_in[22];
    const float* b2      = (const float*)d_in[23];
    const float* ln2_g   = (const float*)d_in[24];
    const float* ln2_b   = (const float*)d_in[25];
    const float* w_dec1  = (const float*)d_in[26];
    const float* b_dec1  = (const float*)d_in[27];
    const float* w_dec2  = (const float*)d_in[28];
    const float* b_dec2  = (const float*)d_in[29];
    const int*   intent  = (const int*)d_in[30];
    float* out = (float*)d_out;

    const size_t WD = (size_t)D_ * D_;
    const size_t WD4 = (size_t)D_ * D4_;
    const size_t kv_elems = (size_t)L_ * B_ * H_ * HD_ * N_;
    const size_t kv_l = (size_t)B_ * H_ * HD_ * N_;

    char* wp = (char*)d_ws;
    ushort* Kt     = (ushort*)wp; wp += kv_elems * 2;
    ushort* Vt     = (ushort*)wp; wp += kv_elems * 2;
    ushort* tokens = (ushort*)wp; wp += (size_t)B_ * N_ * D_ * 2;
    ushort* Wkvt   = (ushort*)wp; wp += 4 * WD * 2;
    ushort* Wqt    = (ushort*)wp; wp += 2 * WD * 2;
    ushort* Wot    = (ushort*)wp; wp += 2 * WD * 2;
    ushort* W1t    = (ushort*)wp; wp += 2 * WD4 * 2;
    ushort* W2t    = (ushort*)wp; wp += 2 * WD4 * 2;
    ushort* dec1t  = (ushort*)wp; wp += WD * 2;
    float* bias_kv = (float*)wp;  wp += 4 * D_ * 4;
    float* bqe     = (float*)wp;  wp += 2 * D_ * 4;
    float* b1e     = (float*)wp;  wp += 2 * D4_ * 4;
    float* xA      = (float*)wp;  wp += (size_t)B_ * D_ * 4;
    float* xB      = (float*)wp;  wp += (size_t)B_ * D_ * 4;
    ushort* h1     = (ushort*)wp; wp += (size_t)B_ * D4_ * 2;
    float* cp      = (float*)wp;  wp += (size_t)B_ * 2 * 4;

    // ---- prep ----
    context_kernel<<<B_, 256, 0, stream>>>(past, w_qinit, b_qinit, intent,
                                           w_pp, b_pp, g_pp, be_pp, time_emb, xA, xB, cp);
    token_prep<<<dim3(12, 4, 256), 256, 0, stream>>>(feats, pos_enc, tokens);
    kvbias_prep<<<12, 256, 0, stream>>>(bk, bv, bias_kv);
    for (int l = 0; l < L_; ++l) {
        transpose_w<<<dim3(24, 24), 256, 0, stream>>>(Wk + l * WD, Wkvt + (2 * l + 0) * WD, nullptr, D_, D_);
        transpose_w<<<dim3(24, 24), 256, 0, stream>>>(Wv + l * WD, Wkvt + (2 * l + 1) * WD, nullptr, D_, D_);
        transpose_w<<<dim3(24, 24), 256, 0, stream>>>(Wq + l * WD, Wqt + l * WD, ln1_g + l * D_, D_, D_);
        transpose_w<<<dim3(24, 24), 256, 0, stream>>>(Wo + l * WD, Wot + l * WD, nullptr, D_, D_);
        transpose_w<<<dim3(96, 24), 256, 0, stream>>>(W1 + l * WD4, W1t + l * WD4, ln2_g + l * D_, D_, D4_);
        transpose_w<<<dim3(24, 96), 256, 0, stream>>>(W2 + l * WD4, W2t + l * WD4, nullptr, D4_, D_);
        bias_eff_kernel<<<12, 256, 0, stream>>>(Wq + l * WD, bq + l * D_, ln1_b + l * D_, bqe + l * D_, D_);
        bias_eff_kernel<<<48, 256, 0, stream>>>(W1 + l * WD4, b1 + l * D4_, ln2_b + l * D_, b1e + l * D4_, D4_);
    }
    transpose_w<<<dim3(24, 24), 256, 0, stream>>>(w_dec1, dec1t, nullptr, D_, D_);

    kv_gemm_mfma<<<dim3(24, 512), 256, 0, stream>>>(tokens, Wkvt, bias_kv, Kt, Vt);

    // ---- sequential steps: 7 kernels/step ----
    // invariant at attn entry: xA == xB == current x
    for (int t = 0; t < T_; ++t) {
        for (int l = 0; l < L_; ++l) {
            // attn reads xA, atomicAdds o@Wo into xB  -> xB = x + attn_out
            attn_fused<<<dim3(H_, B_), 256, 0, stream>>>(xA, Wqt + l * WD, bqe + l * D_,
                                                         Kt + l * kv_l, Vt + l * kv_l,
                                                         Wot + l * WD, bo + l * D_, xB);
            // ffn1 reads xB (LN inline); e0==0 blocks refresh xA := xB
            gemm_s<1, 1, 1, 1><<<dim3(48, 4), 256, 0, stream>>>(xB, W1t + l * WD4,
                                                                b1e + l * D4_, h1, nullptr, xA, D_, D4_);
            // ffn2 atomicAdds into BOTH -> xA == xB == x_next
            gemm_s<0, 2, 0, 4><<<dim3(12, 4, 4), 256, 0, stream>>>(h1, W2t + l * WD4,
                                                                   b2 + l * D_, xB, xA, nullptr, D4_, D_);
        }
        tail_kernel<<<B_, 256, 0, stream>>>(xB, xA, xB, dec1t, b_dec1, w_dec2, b_dec2, cp, out,
                                            time_emb, w_pp, b_pp, g_pp, be_pp, t);
    }
}

// Round 6
// 6697.301 us; speedup vs baseline: 1.2511x; 1.2511x over previous
//
#include <hip/hip_runtime.h>
#include <hip/hip_bf16.h>
#include <math.h>

#define B_ 256
#define D_ 768
#define N_ 256
#define L_ 2
#define H_ 8
#define T_ 20
#define HD_ 96
#define D4_ 3072

typedef float f32x4v __attribute__((ext_vector_type(4)));
typedef __bf16 bf16x8v __attribute__((ext_vector_type(8)));

union V16 { uint4 u; bf16x8v v; };

__device__ __forceinline__ ushort f2b(float f) {
    union { float f; unsigned u; } x{f};
    unsigned r = x.u + 0x7fffu + ((x.u >> 16) & 1u);
    return (ushort)(r >> 16);
}
__device__ __forceinline__ float b2f(ushort s) {
    union { unsigned u; float f; } x{(unsigned)s << 16};
    return x.f;
}
__device__ __forceinline__ float gelu_f(float v) {
    return 0.5f * v * (1.0f + erff(v * 0.7071067811865476f));
}
__device__ __forceinline__ float dot8(const float* __restrict__ xp, uint4 u) {
    return xp[0] * b2f((ushort)(u.x & 0xffffu)) + xp[1] * b2f((ushort)(u.x >> 16))
         + xp[2] * b2f((ushort)(u.y & 0xffffu)) + xp[3] * b2f((ushort)(u.y >> 16))
         + xp[4] * b2f((ushort)(u.z & 0xffffu)) + xp[5] * b2f((ushort)(u.z >> 16))
         + xp[6] * b2f((ushort)(u.w & 0xffffu)) + xp[7] * b2f((ushort)(u.w >> 16));
}
__device__ __forceinline__ float blockSum(float v, float* red, int tid) {
    for (int off = 32; off; off >>= 1) v += __shfl_down(v, off, 64);
    int w = tid >> 6, lane = tid & 63;
    if (lane == 0) red[w] = v;
    __syncthreads();
    float r = red[0] + red[1] + red[2] + red[3];
    __syncthreads();
    return r;
}
// async global->LDS, 16B per lane; lds base must be wave-uniform (lane*16 added by HW)
__device__ __forceinline__ void gl_lds16(const ushort* g, ushort* l) {
    __builtin_amdgcn_global_load_lds((const __attribute__((address_space(1))) unsigned int*)g,
                                     (__attribute__((address_space(3))) unsigned int*)l,
                                     16, 0, 0);
}

// ---------------- context + cp init + prestep(t=0), all per-row ----------------
__global__ __launch_bounds__(256) void context_kernel(const float* __restrict__ past,
                                                      const float* __restrict__ w_qinit,
                                                      const float* __restrict__ b_qinit,
                                                      const int* __restrict__ intent,
                                                      const float* __restrict__ w_pp,
                                                      const float* __restrict__ b_pp,
                                                      const float* __restrict__ g_pp,
                                                      const float* __restrict__ be_pp,
                                                      const float* __restrict__ te0,
                                                      float* __restrict__ x,
                                                      float* __restrict__ cp) {
    int b = blockIdx.x, tid = threadIdx.x;
    __shared__ float ps[96];
    __shared__ int oidx;
    __shared__ float red[4];
    if (tid < 96) ps[tid] = past[b * 96 + tid];
    if (tid == 0) {
        int iv = intent[b] - 1;
        oidx = iv < 0 ? 0 : (iv > 2 ? 2 : iv);
    }
    __syncthreads();
    float ctx[3];
    #pragma unroll
    for (int r = 0; r < 3; ++r) {
        int d = tid + r * 256;
        float acc = w_qinit[oidx * D_ + d] + b_qinit[d];
        #pragma unroll 8
        for (int p = 0; p < 96; ++p) acc += ps[p] * w_qinit[(3 + p) * D_ + d];
        ctx[r] = acc;
    }
    float c0 = ps[90], c1 = ps[91];   // past[:, -1, 0:2]
    if (tid == 0) { cp[b * 2] = c0; cp[b * 2 + 1] = c1; }
    // prestep for t=0
    float t[3];
    float s = 0, ss = 0;
    #pragma unroll
    for (int r = 0; r < 3; ++r) {
        int d = tid + r * 256;
        t[r] = c0 * w_pp[d] + c1 * w_pp[D_ + d] + b_pp[d];
        s += t[r]; ss += t[r] * t[r];
    }
    s = blockSum(s, red, tid);
    ss = blockSum(ss, red, tid);
    float mean = s * (1.0f / D_);
    float var = ss * (1.0f / D_) - mean * mean;
    float rinv = rsqrtf(var + 1e-5f);
    #pragma unroll
    for (int r = 0; r < 3; ++r) {
        int d = tid + r * 256;
        float pq = fmaxf((t[r] - mean) * rinv * g_pp[d] + be_pp[d], 0.0f);
        x[b * D_ + d] = ctx[r] + pq + te0[d];
    }
}

// ---------------- tokens bf16 k-major ----------------
__global__ __launch_bounds__(256) void token_prep(const float* __restrict__ feats,
                                                  const float* __restrict__ pos_enc,
                                                  ushort* __restrict__ tokens) {
    int b = blockIdx.z;
    int d0 = blockIdx.x * 64, n0 = blockIdx.y * 64;
    __shared__ float tile[64][65];
    int tid = threadIdx.x;
    int nl = tid & 63, dl0 = tid >> 6;
    const float* fb = feats + ((size_t)b * D_ + d0) * N_ + n0;
    #pragma unroll
    for (int i = 0; i < 16; ++i) {
        int dl = dl0 + i * 4;
        tile[dl][nl] = fb[(size_t)dl * N_ + nl];
    }
    __syncthreads();
    int dq = (tid & 15) * 4;
    int ng = tid >> 4;
    #pragma unroll
    for (int i = 0; i < 4; ++i) {
        int nl2 = ng + i * 16;
        int n = n0 + nl2;
        float4 p = *(const float4*)(pos_enc + (size_t)n * D_ + d0 + dq);
        ushort4 o;
        o.x = f2b(tile[dq + 0][nl2] + p.x);
        o.y = f2b(tile[dq + 1][nl2] + p.y);
        o.z = f2b(tile[dq + 2][nl2] + p.z);
        o.w = f2b(tile[dq + 3][nl2] + p.w);
        *(ushort4*)&tokens[((size_t)b * N_ + n) * D_ + d0 + dq] = o;
    }
}

// ---------------- weight transpose (+ optional row scale) fp32[K][N] -> bf16[N][K] ----------------
__global__ __launch_bounds__(256) void transpose_w(const float* __restrict__ W,
                                                   ushort* __restrict__ out,
                                                   const float* __restrict__ scale,
                                                   int K, int N) {
    __shared__ float t[32][33];
    int k0 = blockIdx.y * 32, n0 = blockIdx.x * 32;
    int tx = threadIdx.x & 31, ty = threadIdx.x >> 5;
    #pragma unroll
    for (int i = 0; i < 4; ++i)
        t[ty + i * 8][tx] = W[(size_t)(k0 + ty + i * 8) * N + n0 + tx];
    __syncthreads();
    #pragma unroll
    for (int i = 0; i < 4; ++i) {
        int n = n0 + ty + i * 8, k = k0 + tx;
        float v = t[tx][ty + i * 8];
        if (scale) v *= scale[k];
        out[(size_t)n * K + k] = f2b(v);
    }
}

// ---------------- bias_eff = bias + b_ln @ W (parallel k-split) ----------------
__global__ __launch_bounds__(256) void bias_eff_kernel(const float* __restrict__ W,
                                                       const float* __restrict__ bias,
                                                       const float* __restrict__ lb,
                                                       float* __restrict__ be, int Nc) {
    __shared__ float lbs[768];
    __shared__ float part[4][64];
    int tid = threadIdx.x;
    for (int i = tid; i < 768; i += 256) lbs[i] = lb[i];
    __syncthreads();
    int n0 = blockIdx.x * 64;
    int nl = tid & 63, kp = tid >> 6;
    int n = n0 + nl;
    float a = 0.0f;
    #pragma unroll 4
    for (int k = kp * 192; k < kp * 192 + 192; ++k)
        a += lbs[k] * W[(size_t)k * Nc + n];
    part[kp][nl] = a;
    __syncthreads();
    if (tid < 64)
        be[n0 + tid] = bias[n0 + tid] + part[0][tid] + part[1][tid] + part[2][tid] + part[3][tid];
}

__global__ void kvbias_prep(const float* __restrict__ bk, const float* __restrict__ bv,
                            float* __restrict__ bc) {
    int i = blockIdx.x * 256 + threadIdx.x;
    int mi = i / D_, c = i % D_;
    int l = mi >> 1;
    bc[i] = (mi & 1 ? bv : bk)[l * D_ + c];
}

// ---------------- K/V projection MFMA GEMM (both K and V stored hd-major [.. hd][n]) ----------------
// 3-buffer, 2-tile-ahead global_load_lds pipeline with counted vmcnt (T4 pattern)
__global__ __launch_bounds__(256) void kv_gemm_mfma(const ushort* __restrict__ tokens,
                                                    const ushort* __restrict__ Wkvt,
                                                    const float* __restrict__ bias_kv,
                                                    ushort* __restrict__ Kt,
                                                    ushort* __restrict__ Vt) {
    int e0 = blockIdx.x * 128;
    int mi = e0 / D_;
    int ein = e0 % D_;
    int l = mi >> 1, isV = mi & 1;
    int m0 = blockIdx.y * 128;
    int b = m0 >> 8, ntok0 = m0 & 255;
    __shared__ __align__(16) ushort smem[24576];   // 3 x 8192 staging; epilogue Ct reuses [0..17407]
    int tid = threadIdx.x;
    int w = tid >> 6, lane = tid & 63, quad = lane >> 4, l16 = lane & 15;
    int wr = w >> 1, wc = w & 1;
    f32x4v acc[4][4];
    #pragma unroll
    for (int i = 0; i < 4; ++i)
        #pragma unroll
        for (int j = 0; j < 4; ++j) acc[i][j] = (f32x4v)(0.0f);

    // each stage issues 4 loads/thread
    auto stage = [&](int buf, int k0) {
        ushort* Ab = smem + buf * 8192;
        ushort* Bb = Ab + 4096;
        #pragma unroll
        for (int vv = 0; vv < 2; ++vv) {
            int v = tid + vv * 256;
            int row = v >> 2, kv = v & 3;
            gl_lds16(&tokens[(size_t)(m0 + row) * D_ + k0 + kv * 8], Ab + w * 512 + vv * 2048);
            gl_lds16(&Wkvt[(size_t)(e0 + row) * D_ + k0 + kv * 8],   Bb + w * 512 + vv * 2048);
        }
    };
    auto compute = [&](int buf) {
        const ushort* Ab = smem + buf * 8192;
        const ushort* Bb = Ab + 4096;
        V16 a[4], bb[4];
        #pragma unroll
        for (int i = 0; i < 4; ++i)
            a[i].u = *(const uint4*)&Ab[(wr * 64 + i * 16 + l16) * 32 + quad * 8];
        #pragma unroll
        for (int j = 0; j < 4; ++j)
            bb[j].u = *(const uint4*)&Bb[(wc * 64 + j * 16 + l16) * 32 + quad * 8];
        #pragma unroll
        for (int i = 0; i < 4; ++i)
            #pragma unroll
            for (int j = 0; j < 4; ++j)
                acc[i][j] = __builtin_amdgcn_mfma_f32_16x16x32_bf16(a[i].v, bb[j].v, acc[i][j], 0, 0, 0);
    };

    // prologue: tiles 0 and 1 in flight; require tile 0 complete (allow tile 1's 4 loads outstanding)
    stage(0, 0);
    stage(1, 32);
    asm volatile("s_waitcnt vmcnt(4)" ::: "memory");
    __syncthreads();
    // steady state: compute(t) while tile t+1 is landing and tile t+2 is issued
    #define NT_ (D_ / 32)
    for (int t = 0; t < NT_; ++t) {
        if (t + 2 < NT_) stage((t + 2) % 3, (t + 2) * 32);
        compute(t % 3);
        if (t + 2 < NT_) {
            asm volatile("s_waitcnt vmcnt(4)" ::: "memory");   // tile t+1 done, t+2 stays in flight
            __syncthreads();
        } else if (t + 1 < NT_) {
            asm volatile("s_waitcnt vmcnt(0)" ::: "memory");   // drain: last prefetched tile
            __syncthreads();
        }
    }
    #undef NT_
    __syncthreads();   // protect smem reuse (epilogue Ct overlaps staging buffers)

    float bcol[4];
    #pragma unroll
    for (int j = 0; j < 4; ++j)
        bcol[j] = bias_kv[e0 + wc * 64 + j * 16 + l16];

    ushort* Ct = smem;
    ushort* outbuf = isV ? Vt : Kt;
    #pragma unroll
    for (int i = 0; i < 4; ++i)
        #pragma unroll
        for (int j = 0; j < 4; ++j) {
            int e_l = wc * 64 + j * 16 + l16;
            int m_b = wr * 64 + i * 16 + quad * 4;
            ushort4 p;
            p.x = f2b(acc[i][j][0] + bcol[j]);
            p.y = f2b(acc[i][j][1] + bcol[j]);
            p.z = f2b(acc[i][j][2] + bcol[j]);
            p.w = f2b(acc[i][j][3] + bcol[j]);
            *(ushort4*)&Ct[e_l * 136 + m_b] = p;
        }
    __syncthreads();
    int e_l = tid >> 1, half = tid & 1;
    int c = ein + e_l;
    int h = c / HD_, hd = c % HD_;
    size_t dst = ((((size_t)l * B_ + b) * H_ + h) * HD_ + hd) * N_ + ntok0 + half * 64;
    #pragma unroll
    for (int p8 = 0; p8 < 8; ++p8)
        *(uint4*)&outbuf[dst + p8 * 8] = *(const uint4*)&Ct[e_l * 136 + half * 64 + p8 * 8];
}

// ---------------- small MFMA GEMM, async 2-phase pipeline, swizzled LDS ----------------
// AVAR: 0 = bf16 A (global_load_lds), 1 = fp32 A normalized by inline row stats (reg path)
// OMODE: 0 = bf16 store, 1 = gelu->bf16 store, 2 = fp32 atomicAdd (bias on z==0)
template<int AVAR, int OMODE, int STATS, int KSPLIT>
__global__ __launch_bounds__(256) void gemm_s(const void* __restrict__ Av,
                                              const ushort* __restrict__ Bt,
                                              const float* __restrict__ bias,
                                              void* __restrict__ Cv,
                                              int K, int Nc) {
    __shared__ __align__(16) ushort As[2][2048];
    __shared__ __align__(16) ushort Bs[2][2048];
    __shared__ float smst[64][2];
    int tid = threadIdx.x;
    int m0 = blockIdx.y * 64, e0 = blockIdx.x * 64;
    int kslice = K / KSPLIT;
    int kbeg = blockIdx.z * kslice, kend = kbeg + kslice;
    int w = tid >> 6, lane = tid & 63, quad = lane >> 4, l16 = lane & 15;
    int swz = (l16 >> 1) & 3;
    int rchunk = ((quad ^ swz) & 3) * 8;

    if (STATS) {
        // inline LN stats for rows m0..m0+63 (4 threads/row, K==768)
        int row = tid >> 2, part = tid & 3;
        const float* xr = (const float*)Av + (size_t)(m0 + row) * K + part * 192;
        float s = 0, ss = 0;
        #pragma unroll 4
        for (int i = 0; i < 192; i += 4) {
            float4 f = *(const float4*)(xr + i);
            s += f.x + f.y + f.z + f.w;
            ss += f.x * f.x + f.y * f.y + f.z * f.z + f.w * f.w;
        }
        s += __shfl_xor(s, 1, 64);  s += __shfl_xor(s, 2, 64);
        ss += __shfl_xor(ss, 1, 64); ss += __shfl_xor(ss, 2, 64);
        if (part == 0) {
            float mean = s * (1.0f / 768.0f);
            float var = ss * (1.0f / 768.0f) - mean * mean;
            smst[row][0] = mean;
            smst[row][1] = rsqrtf(var + 1e-5f);
        }
        __syncthreads();
    }

    bool doA = w < 2;
    int t2 = tid & 127;
    f32x4v acc[4];
    #pragma unroll
    for (int i = 0; i < 4; ++i) acc[i] = (f32x4v)(0.0f);

    auto fetchA1 = [&](int kk, int vv) -> uint4 {
        int v = t2 + vv * 128;
        int row = v >> 2, kq = v & 3;
        const float* Af = (const float*)Av + (size_t)(m0 + row) * K + kk + kq * 8;
        float4 f0 = *(const float4*)Af;
        float4 f1 = *(const float4*)(Af + 4);
        float mn = smst[row][0], rs = smst[row][1];
        f0.x = (f0.x - mn) * rs; f0.y = (f0.y - mn) * rs;
        f0.z = (f0.z - mn) * rs; f0.w = (f0.w - mn) * rs;
        f1.x = (f1.x - mn) * rs; f1.y = (f1.y - mn) * rs;
        f1.z = (f1.z - mn) * rs; f1.w = (f1.w - mn) * rs;
        uint4 u;
        u.x = (unsigned)f2b(f0.x) | ((unsigned)f2b(f0.y) << 16);
        u.y = (unsigned)f2b(f0.z) | ((unsigned)f2b(f0.w) << 16);
        u.z = (unsigned)f2b(f1.x) | ((unsigned)f2b(f1.y) << 16);
        u.w = (unsigned)f2b(f1.z) | ((unsigned)f2b(f1.w) << 16);
        return u;
    };
    auto stashA = [&](int buf, int vv, uint4 u) {
        int v = t2 + vv * 128;
        int row = v >> 2, kq = v & 3;
        *(uint4*)&As[buf][row * 32 + ((kq ^ ((row >> 1) & 3)) & 3) * 8] = u;
    };
    auto stageA0 = [&](int buf, int kk) {
        #pragma unroll
        for (int vv = 0; vv < 2; ++vv) {
            int v = t2 + vv * 128;
            int row = v >> 2;
            int kq = (v & 3) ^ ((row >> 1) & 3);
            gl_lds16((const ushort*)Av + (size_t)(m0 + row) * K + kk + kq * 8,
                     &As[buf][w * 512 + vv * 1024]);
        }
    };
    auto stageB = [&](int buf, int kk) {
        int wb = w - 2;
        #pragma unroll
        for (int vv = 0; vv < 2; ++vv) {
            int v = t2 + vv * 128;
            int row = v >> 2;
            int kq = (v & 3) ^ ((row >> 1) & 3);
            gl_lds16(&Bt[(size_t)(e0 + row) * K + kk + kq * 8],
                     &Bs[buf][wb * 512 + vv * 1024]);
        }
    };
    auto compute = [&](int buf) {
        V16 bb;
        bb.u = *(const uint4*)&Bs[buf][(w * 16 + l16) * 32 + rchunk];
        #pragma unroll
        for (int i = 0; i < 4; ++i) {
            V16 a;
            a.u = *(const uint4*)&As[buf][(i * 16 + l16) * 32 + rchunk];
            acc[i] = __builtin_amdgcn_mfma_f32_16x16x32_bf16(a.v, bb.v, acc[i], 0, 0, 0);
        }
    };

    // prologue
    if (doA) {
        if (AVAR == 0) {
            stageA0(0, kbeg);
        } else {
            uint4 p0 = fetchA1(kbeg, 0), p1 = fetchA1(kbeg, 1);
            stashA(0, 0, p0); stashA(0, 1, p1);
        }
    } else {
        stageB(0, kbeg);
    }
    asm volatile("s_waitcnt vmcnt(0)" ::: "memory");
    __syncthreads();
    int cur = 0;
    for (int kk = kbeg + 32; kk < kend; kk += 32) {
        uint4 p0, p1;
        if (doA) {
            if (AVAR == 0) stageA0(cur ^ 1, kk);
            else { p0 = fetchA1(kk, 0); p1 = fetchA1(kk, 1); }
        } else {
            stageB(cur ^ 1, kk);
        }
        compute(cur);
        if (AVAR == 1 && doA) { stashA(cur ^ 1, 0, p0); stashA(cur ^ 1, 1, p1); }
        asm volatile("s_waitcnt vmcnt(0)" ::: "memory");
        __syncthreads();
        cur ^= 1;
    }
    compute(cur);

    int n = e0 + w * 16 + l16;
    float bn = 0.0f;
    if (OMODE != 2 || blockIdx.z == 0) bn = bias[n];
    #pragma unroll
    for (int i = 0; i < 4; ++i) {
        #pragma unroll
        for (int r = 0; r < 4; ++r) {
            int m = m0 + i * 16 + quad * 4 + r;
            float v = acc[i][r] + bn;
            if (OMODE == 1) v = gelu_f(v);
            if (OMODE == 2) atomicAdd((float*)Cv + (size_t)m * Nc + n, v);
            else            ((ushort*)Cv)[(size_t)m * Nc + n] = f2b(v);
        }
    }
}

// ---------------- fused LN1 + Q-projection + attention ----------------
// one block per (b,h); K and V both hd-major: [.., hd, n]
__global__ __launch_bounds__(256) void attn_fused(const float* __restrict__ x,
                                                  const ushort* __restrict__ Wqt,
                                                  const float* __restrict__ bqe,
                                                  const ushort* __restrict__ Kt,
                                                  const ushort* __restrict__ Vt,
                                                  ushort* __restrict__ att) {
    int b = blockIdx.y, h = blockIdx.x, tid = threadIdx.x;
    int w = tid >> 6, lane = tid & 63;
    __shared__ float xs[768];
    __shared__ float red[4];
    __shared__ float qs[96];
    __shared__ float spart[4][256];
    __shared__ float sc[256];
    __shared__ float opo[96];

    if (tid < 192) *(float4*)&xs[tid * 4] = *(const float4*)&x[(size_t)b * D_ + tid * 4];
    __syncthreads();

    // LN stats over the row
    float s = 0, ss = 0;
    #pragma unroll
    for (int r = 0; r < 3; ++r) { float v = xs[tid + r * 256]; s += v; ss += v * v; }
    s = blockSum(s, red, tid);
    ss = blockSum(ss, red, tid);
    float mean = s * (1.0f / D_);
    float var = ss * (1.0f / D_) - mean * mean;
    float rinv = rsqrtf(var + 1e-5f);
    #pragma unroll
    for (int r = 0; r < 3; ++r) { int d = tid + r * 256; xs[d] = (xs[d] - mean) * rinv; }
    __syncthreads();

    // Q projection for this head's 96 columns: 192 threads, (col, k-half)
    if (tid < 192) {
        int j = tid >> 1, kh = tid & 1;
        const ushort* wr = Wqt + (size_t)(h * HD_ + j) * D_ + kh * 384;
        const float* xp = xs + kh * 384;
        float acc = 0.0f;
        #pragma unroll 4
        for (int k = 0; k < 384; k += 8)
            acc += dot8(xp + k, *(const uint4*)&wr[k]);
        acc += __shfl_xor(acc, 1, 64);
        if (kh == 0) qs[j] = (acc + bqe[h * HD_ + j]) * 0.10206207261596575f;
    }
    __syncthreads();

    // scores: wave w -> hd rows [w*24, w*24+24); lane: r2 = hd parity, tg covers 8 tokens (uint4)
    {
        int r2 = lane >> 5, tg = lane & 31;
        const ushort* Kp = Kt + (size_t)(b * H_ + h) * HD_ * N_;
        float s8[8];
        #pragma unroll
        for (int j = 0; j < 8; ++j) s8[j] = 0.0f;
        #pragma unroll 4
        for (int i = 0; i < 12; ++i) {
            int hd = w * 24 + i * 2 + r2;
            uint4 kk = *(const uint4*)&Kp[hd * N_ + tg * 8];
            float qv = qs[hd];
            s8[0] += qv * b2f((ushort)(kk.x & 0xffffu));
            s8[1] += qv * b2f((ushort)(kk.x >> 16));
            s8[2] += qv * b2f((ushort)(kk.y & 0xffffu));
            s8[3] += qv * b2f((ushort)(kk.y >> 16));
            s8[4] += qv * b2f((ushort)(kk.z & 0xffffu));
            s8[5] += qv * b2f((ushort)(kk.z >> 16));
            s8[6] += qv * b2f((ushort)(kk.w & 0xffffu));
            s8[7] += qv * b2f((ushort)(kk.w >> 16));
        }
        #pragma unroll
        for (int j = 0; j < 8; ++j) s8[j] += __shfl_xor(s8[j], 32, 64);
        if (r2 == 0) {
            float4 lo, hi;
            lo.x = s8[0]; lo.y = s8[1]; lo.z = s8[2]; lo.w = s8[3];
            hi.x = s8[4]; hi.y = s8[5]; hi.z = s8[6]; hi.w = s8[7];
            *(float4*)&spart[w][tg * 8] = lo;
            *(float4*)&spart[w][tg * 8 + 4] = hi;
        }
    }
    __syncthreads();

    // softmax over 256 tokens (token n = tid)
    float sv = spart[0][tid] + spart[1][tid] + spart[2][tid] + spart[3][tid];
    float m = sv;
    for (int off = 32; off; off >>= 1) m = fmaxf(m, __shfl_xor(m, off, 64));
    if (lane == 0) red[w] = m;
    __syncthreads();
    m = fmaxf(fmaxf(red[0], red[1]), fmaxf(red[2], red[3]));
    __syncthreads();
    float e = expf(sv - m);
    float tot = blockSum(e, red, tid);
    sc[tid] = e / tot;
    __syncthreads();

    // PV: 192 threads, (hd, n-half); V row contiguous over n -> uint4 loads
    if (tid < 192) {
        int hd = tid >> 1, nh = tid & 1;
        const ushort* Vr = Vt + (size_t)(b * H_ + h) * HD_ * N_ + hd * N_ + nh * 128;
        const float* scp = sc + nh * 128;
        float o = 0.0f;
        #pragma unroll 4
        for (int i = 0; i < 16; ++i)
            o += dot8(scp + i * 8, *(const uint4*)&Vr[i * 8]);
        o += __shfl_xor(o, 1, 64);
        if (nh == 0) opo[hd] = o;
    }
    __syncthreads();
    if (tid < 96) att[(size_t)b * D_ + h * HD_ + tid] = f2b(opo[tid]);
}

// ---------------- tail: dec1 matvec + gelu + dec2 + cp update + out + prestep(t+1) ----------------
__global__ __launch_bounds__(256) void tail_kernel(float* __restrict__ x,
                                                   const ushort* __restrict__ dec1t,
                                                   const float* __restrict__ b_dec1,
                                                   const float* __restrict__ w_dec2,
                                                   const float* __restrict__ b_dec2,
                                                   float* __restrict__ cp,
                                                   float* __restrict__ out,
                                                   const float* __restrict__ time_emb,
                                                   const float* __restrict__ w_pp,
                                                   const float* __restrict__ b_pp,
                                                   const float* __restrict__ g_pp,
                                                   const float* __restrict__ be_pp,
                                                   int t) {
    int b = blockIdx.x, tid = threadIdx.x;
    __shared__ float xs[768];
    __shared__ float red[4];
    #pragma unroll
    for (int r = 0; r < 3; ++r) xs[tid + r * 256] = x[b * D_ + tid + r * 256];
    __syncthreads();
    float d0 = 0, d1 = 0, d2 = 0;
    const ushort* w0 = dec1t + (size_t)tid * D_;
    const ushort* w1 = w0 + (size_t)256 * D_;
    const ushort* w2 = w0 + (size_t)512 * D_;
    #pragma unroll 2
    for (int k = 0; k < 768; k += 8) {
        d0 += dot8(xs + k, *(const uint4*)&w0[k]);
        d1 += dot8(xs + k, *(const uint4*)&w1[k]);
        d2 += dot8(xs + k, *(const uint4*)&w2[k]);
    }
    float v0 = gelu_f(d0 + b_dec1[tid]);
    float v1 = gelu_f(d1 + b_dec1[tid + 256]);
    float v2 = gelu_f(d2 + b_dec1[tid + 512]);
    float p0 = v0 * w_dec2[tid * 2]     + v1 * w_dec2[(tid + 256) * 2]     + v2 * w_dec2[(tid + 512) * 2];
    float p1 = v0 * w_dec2[tid * 2 + 1] + v1 * w_dec2[(tid + 256) * 2 + 1] + v2 * w_dec2[(tid + 512) * 2 + 1];
    p0 = blockSum(p0, red, tid);
    p1 = blockSum(p1, red, tid);
    float c0 = cp[b * 2] + p0 + b_dec2[0];
    float c1 = cp[b * 2 + 1] + p1 + b_dec2[1];
    if (tid == 0) {
        cp[b * 2] = c0;
        cp[b * 2 + 1] = c1;
        out[(b * T_ + t) * 2] = c0;
        out[(b * T_ + t) * 2 + 1] = c1;
    }
    if (t < T_ - 1) {
        const float* te = time_emb + (size_t)(t + 1) * D_;
        float tv[3];
        float s = 0, ss = 0;
        #pragma unroll
        for (int r = 0; r < 3; ++r) {
            int d = tid + r * 256;
            tv[r] = c0 * w_pp[d] + c1 * w_pp[D_ + d] + b_pp[d];
            s += tv[r]; ss += tv[r] * tv[r];
        }
        s = blockSum(s, red, tid);
        ss = blockSum(ss, red, tid);
        float mean = s * (1.0f / D_);
        float var = ss * (1.0f / D_) - mean * mean;
        float rinv = rsqrtf(var + 1e-5f);
        #pragma unroll
        for (int r = 0; r < 3; ++r) {
            int d = tid + r * 256;
            float pq = fmaxf((tv[r] - mean) * rinv * g_pp[d] + be_pp[d], 0.0f);
            x[b * D_ + d] += pq + te[d];
        }
    }
}

extern "C" void kernel_launch(void* const* d_in, const int* in_sizes, int n_in,
                              void* d_out, int out_size, void* d_ws, size_t ws_size,
                              hipStream_t stream) {
    const float* feats   = (const float*)d_in[0];
    const float* past    = (const float*)d_in[1];
    const float* w_qinit = (const float*)d_in[2];
    const float* b_qinit = (const float*)d_in[3];
    const float* pos_enc = (const float*)d_in[4];
    const float* w_pp    = (const float*)d_in[5];
    const float* b_pp    = (const float*)d_in[6];
    const float* g_pp    = (const float*)d_in[7];
    const float* be_pp   = (const float*)d_in[8];
    const float* time_emb= (const float*)d_in[9];
    const float* Wq      = (const float*)d_in[10];
    const float* bq      = (const float*)d_in[11];
    const float* Wk      = (const float*)d_in[12];
    const float* bk      = (const float*)d_in[13];
    const float* Wv      = (const float*)d_in[14];
    const float* bv      = (const float*)d_in[15];
    const float* Wo      = (const float*)d_in[16];
    const float* bo      = (const float*)d_in[17];
    const float* ln1_g   = (const float*)d_in[18];
    const float* ln1_b   = (const float*)d_in[19];
    const float* W1      = (const float*)d_in[20];
    const float* b1      = (const float*)d_in[21];
    const float* W2      = (const float*)d_in[22];
    const float* b2      = (const float*)d_in[23];
    const float* ln2_g   = (const float*)d_in[24];
    const float* ln2_b   = (const float*)d_in[25];
    const float* w_dec1  = (const float*)d_in[26];
    const float* b_dec1  = (const float*)d_in[27];
    const float* w_dec2  = (const float*)d_in[28];
    const float* b_dec2  = (const float*)d_in[29];
    const int*   intent  = (const int*)d_in[30];
    float* out = (float*)d_out;

    const size_t WD = (size_t)D_ * D_;
    const size_t WD4 = (size_t)D_ * D4_;
    const size_t kv_elems = (size_t)L_ * B_ * H_ * HD_ * N_;
    const size_t kv_l = (size_t)B_ * H_ * HD_ * N_;

    char* wp = (char*)d_ws;
    ushort* Kt     = (ushort*)wp; wp += kv_elems * 2;
    ushort* Vt     = (ushort*)wp; wp += kv_elems * 2;
    ushort* tokens = (ushort*)wp; wp += (size_t)B_ * N_ * D_ * 2;
    ushort* Wkvt   = (ushort*)wp; wp += 4 * WD * 2;
    ushort* Wqt    = (ushort*)wp; wp += 2 * WD * 2;
    ushort* Wot    = (ushort*)wp; wp += 2 * WD * 2;
    ushort* W1t    = (ushort*)wp; wp += 2 * WD4 * 2;
    ushort* W2t    = (ushort*)wp; wp += 2 * WD4 * 2;
    ushort* dec1t  = (ushort*)wp; wp += WD * 2;
    float* bias_kv = (float*)wp;  wp += 4 * D_ * 4;
    float* bqe     = (float*)wp;  wp += 2 * D_ * 4;
    float* b1e     = (float*)wp;  wp += 2 * D4_ * 4;
    float* x       = (float*)wp;  wp += (size_t)B_ * D_ * 4;
    ushort* attbuf = (ushort*)wp; wp += (size_t)B_ * D_ * 2;
    ushort* h1     = (ushort*)wp; wp += (size_t)B_ * D4_ * 2;
    float* cp      = (float*)wp;  wp += (size_t)B_ * 2 * 4;

    // ---- prep ----
    context_kernel<<<B_, 256, 0, stream>>>(past, w_qinit, b_qinit, intent,
                                           w_pp, b_pp, g_pp, be_pp, time_emb, x, cp);
    token_prep<<<dim3(12, 4, 256), 256, 0, stream>>>(feats, pos_enc, tokens);
    kvbias_prep<<<12, 256, 0, stream>>>(bk, bv, bias_kv);
    for (int l = 0; l < L_; ++l) {
        transpose_w<<<dim3(24, 24), 256, 0, stream>>>(Wk + l * WD, Wkvt + (2 * l + 0) * WD, nullptr, D_, D_);
        transpose_w<<<dim3(24, 24), 256, 0, stream>>>(Wv + l * WD, Wkvt + (2 * l + 1) * WD, nullptr, D_, D_);
        transpose_w<<<dim3(24, 24), 256, 0, stream>>>(Wq + l * WD, Wqt + l * WD, ln1_g + l * D_, D_, D_);
        transpose_w<<<dim3(24, 24), 256, 0, stream>>>(Wo + l * WD, Wot + l * WD, nullptr, D_, D_);
        transpose_w<<<dim3(96, 24), 256, 0, stream>>>(W1 + l * WD4, W1t + l * WD4, ln2_g + l * D_, D_, D4_);
        transpose_w<<<dim3(24, 96), 256, 0, stream>>>(W2 + l * WD4, W2t + l * WD4, nullptr, D4_, D_);
        bias_eff_kernel<<<12, 256, 0, stream>>>(Wq + l * WD, bq + l * D_, ln1_b + l * D_, bqe + l * D_, D_);
        bias_eff_kernel<<<48, 256, 0, stream>>>(W1 + l * WD4, b1 + l * D4_, ln2_b + l * D_, b1e + l * D4_, D4_);
    }
    transpose_w<<<dim3(24, 24), 256, 0, stream>>>(w_dec1, dec1t, nullptr, D_, D_);

    kv_gemm_mfma<<<dim3(24, 512), 256, 0, stream>>>(tokens, Wkvt, bias_kv, Kt, Vt);

    // ---- sequential steps: 9 kernels/step ----
    for (int t = 0; t < T_; ++t) {
        for (int l = 0; l < L_; ++l) {
            attn_fused<<<dim3(H_, B_), 256, 0, stream>>>(x, Wqt + l * WD, bqe + l * D_,
                                                         Kt + l * kv_l, Vt + l * kv_l, attbuf);
            gemm_s<0, 2, 0, 4><<<dim3(12, 4, 4), 256, 0, stream>>>(attbuf, Wot + l * WD,
                                                                   bo + l * D_, x, D_, D_);
            gemm_s<1, 1, 1, 1><<<dim3(48, 4), 256, 0, stream>>>(x, W1t + l * WD4,
                                                                b1e + l * D4_, h1, D_, D4_);
            gemm_s<0, 2, 0, 4><<<dim3(12, 4, 4), 256, 0, stream>>>(h1, W2t + l * WD4,
                                                                   b2 + l * D_, x, D4_, D_);
        }
        tail_kernel<<<B_, 256, 0, stream>>>(x, dec1t, b_dec1, w_dec2, b_dec2, cp, out,
                                            time_emb, w_pp, b_pp, g_pp, be_pp, t);
    }
}